// Round 1
// baseline (303.610 us; speedup 1.0000x reference)
//
#include <hip/hip_runtime.h>

#define NN 8192     // nodes
#define NB 32       // graphs
#define NG 256      // nodes per graph
#define NE 65536    // edges
#define DK 512
#define HC 32
#define DB 2048     // body visual dim
#define DF 512      // face visual dim

__device__ __forceinline__ float bf2f(unsigned short u) {
    return __uint_as_float(((unsigned int)u) << 16);
}
__device__ __forceinline__ unsigned short f2bf(float f) {
    unsigned int u = __float_as_uint(f);
    u += 0x7fffu + ((u >> 16) & 1u);   // round-to-nearest-even
    return (unsigned short)(u >> 16);
}

// stats[0..3] = M_ab = sum_d Wq[a][d]*Wk[b][d]  (M00,M01,M10,M11)
// stats[4..5] = sum_d Wv[a][d]
// stats[6..8] = sum_d Wv[a][d]*Wv[b][d]  (q00,q01,q11)
__global__ void stats_kernel(const float* __restrict__ Wq, const float* __restrict__ Wk,
                             const float* __restrict__ Wv, float* __restrict__ stats) {
    const int lane = threadIdx.x;  // 64 threads
    float m00=0,m01=0,m10=0,m11=0,s0=0,s1=0,q00=0,q01=0,q11=0;
    for (int d = lane; d < DK; d += 64) {
        float q0=Wq[d], q1=Wq[DK+d];
        float k0=Wk[d], k1=Wk[DK+d];
        float v0=Wv[d], v1=Wv[DK+d];
        m00 += q0*k0; m01 += q0*k1; m10 += q1*k0; m11 += q1*k1;
        s0 += v0; s1 += v1;
        q00 += v0*v0; q01 += v0*v1; q11 += v1*v1;
    }
    #pragma unroll
    for (int off = 32; off > 0; off >>= 1) {
        m00 += __shfl_down(m00,off); m01 += __shfl_down(m01,off);
        m10 += __shfl_down(m10,off); m11 += __shfl_down(m11,off);
        s0  += __shfl_down(s0,off);  s1  += __shfl_down(s1,off);
        q00 += __shfl_down(q00,off); q01 += __shfl_down(q01,off);
        q11 += __shfl_down(q11,off);
    }
    if (lane == 0) {
        stats[0]=m00; stats[1]=m01; stats[2]=m10; stats[3]=m11;
        stats[4]=s0;  stats[5]=s1;  stats[6]=q00; stats[7]=q01; stats[8]=q11;
    }
}

// Normalize one visual row per block. BF16 path writes normalized row in bf16;
// fp32 path writes only the inverse norm.
template<int D, bool BF16>
__global__ __launch_bounds__(256) void norm_kernel(const float* __restrict__ v,
        unsigned short* __restrict__ vn, float* __restrict__ invn) {
    __shared__ float red[4];
    __shared__ float s_inv;
    const int node = blockIdx.x;
    const int tid = threadIdx.x;
    const float4* row = (const float4*)(v + (size_t)node * D);
    float ss = 0.f;
    for (int c = tid; c < D/4; c += 256) {
        float4 x = row[c];
        ss += x.x*x.x + x.y*x.y + x.z*x.z + x.w*x.w;
    }
    #pragma unroll
    for (int off = 32; off > 0; off >>= 1) ss += __shfl_down(ss, off);
    if ((tid & 63) == 0) red[tid >> 6] = ss;
    __syncthreads();
    if (tid == 0) s_inv = rsqrtf(red[0]+red[1]+red[2]+red[3] + 1e-8f);
    __syncthreads();
    const float inv = s_inv;
    if (BF16) {
        ushort4* orow = (ushort4*)(vn + (size_t)node * D);
        for (int c = tid; c < D/4; c += 256) {
            float4 x = row[c];
            orow[c] = make_ushort4(f2bf(x.x*inv), f2bf(x.y*inv),
                                   f2bf(x.z*inv), f2bf(x.w*inv));
        }
    } else {
        if (tid == 0) invn[node] = inv;
    }
}

// Rank-2 attention: one block per graph, one thread per query node.
__global__ __launch_bounds__(256) void attn_kernel(const float* __restrict__ x,
        const float* __restrict__ stats, float* __restrict__ a) {
    __shared__ float2 xs[NG];
    const int g = blockIdx.x, i = threadIdx.x;
    xs[i] = ((const float2*)x)[g*NG + i];
    __syncthreads();
    const float scale = 0.04419417382415922f;  // 1/sqrt(512)
    const float2 xi = xs[i];
    const float u0 = (xi.x*stats[0] + xi.y*stats[2]) * scale;
    const float u1 = (xi.x*stats[1] + xi.y*stats[3]) * scale;
    float m = -1e30f;
    for (int j = 0; j < NG; j++) {
        float s = u0*xs[j].x + u1*xs[j].y;
        m = fmaxf(m, s);
    }
    float S = 0.f, a0 = 0.f, a1 = 0.f;
    for (int j = 0; j < NG; j++) {
        float2 xj = xs[j];
        float p = __expf(u0*xj.x + u1*xj.y - m);
        S += p; a0 += p*xj.x; a1 += p*xj.y;
    }
    const float invS = 1.f / S;
    ((float2*)a)[g*NG + i] = make_float2(a0*invS, a1*invS);
}

// Per node (one wave each): reconstruct 512-d attn output from (a0,a1),
// closed-form LN stats, PReLU, 512->32 MLP, node score, and precompute
// h @ body_W / h @ face_W.
__global__ __launch_bounds__(256) void node_kernel(
        const float* __restrict__ a, const float* __restrict__ stats,
        const float* __restrict__ Wv,
        const float* __restrict__ ln_g, const float* __restrict__ ln_b,
        const float* __restrict__ prelu_a,
        const float* __restrict__ mlp_W, const float* __restrict__ mlp_b,
        const float* __restrict__ np_W, const float* __restrict__ np_b,
        const float* __restrict__ body_W, const float* __restrict__ body_b,
        const float* __restrict__ face_W, const float* __restrict__ face_b,
        float* __restrict__ ns, float* __restrict__ hlb, float* __restrict__ hlf) {
    __shared__ float t[4][DK];
    __shared__ float hbuf[4][HC];
    const int wave = threadIdx.x >> 6, lane = threadIdx.x & 63;
    const int node = blockIdx.x * 4 + wave;
    const float a0 = a[node*2], a1 = a[node*2+1];
    const float mean = (a0*stats[4] + a1*stats[5]) * (1.f/DK);
    const float msq  = (a0*a0*stats[6] + 2.f*a0*a1*stats[7] + a1*a1*stats[8]) * (1.f/DK);
    const float inv  = rsqrtf(msq - mean*mean + 1e-5f);
    const float alpha = prelu_a[0];
    const float4* wv0 = (const float4*)Wv;
    const float4* wv1 = (const float4*)(Wv + DK);
    const float4* g4 = (const float4*)ln_g;
    const float4* b4 = (const float4*)ln_b;
    #pragma unroll
    for (int k = 0; k < 2; k++) {
        int c4 = lane*2 + k;
        float4 w0 = wv0[c4], w1 = wv1[c4], gg = g4[c4], bb = b4[c4];
        const float* w0f = (const float*)&w0;
        const float* w1f = (const float*)&w1;
        const float* ggf = (const float*)&gg;
        const float* bbf = (const float*)&bb;
        #pragma unroll
        for (int e2 = 0; e2 < 4; e2++) {
            float od = a0*w0f[e2] + a1*w1f[e2];
            float nd = (od - mean) * inv * ggf[e2] + bbf[e2];
            t[wave][c4*4 + e2] = (nd >= 0.f) ? nd : alpha*nd;
        }
    }
    __syncthreads();
    // h_c = sum_d t[d] * mlp_W[d][c]; split d-range across the two half-waves
    const int c = lane & 31, half = lane >> 5;
    const float* tw = t[wave];
    const float* tp = tw + half*256;
    const float* mw = mlp_W + half*256*HC + c;
    float part = 0.f;
    for (int d = 0; d < 256; d++) part += tp[d] * mw[d*HC];
    part += __shfl_down(part, 32);
    float hc = 0.f;
    if (lane < 32) { hc = part + mlp_b[c]; hbuf[wave][c] = hc; }
    __syncthreads();
    // node score
    float sp = (lane < 32) ? hc * np_W[c] : 0.f;
    #pragma unroll
    for (int off = 16; off > 0; off >>= 1) sp += __shfl_down(sp, off);
    if (lane == 0) ns[node] = sp + np_b[0];
    // per-node linear for both convs
    const float* hb_ = hbuf[wave];
    if (lane < 32) {
        float acc2 = body_b[c];
        #pragma unroll 8
        for (int cp = 0; cp < HC; cp++) acc2 += hb_[cp] * body_W[cp*HC + c];
        hlb[(size_t)node*HC + c] = acc2;
    } else {
        float acc2 = face_b[c];
        #pragma unroll 8
        for (int cp = 0; cp < HC; cp++) acc2 += hb_[cp] * face_W[cp*HC + c];
        hlf[(size_t)node*HC + c] = acc2;
    }
}

// One wave per edge: cosine via dot of (pre-normalized) rows, then 32 lanes
// atomically scatter the 32-channel message into acc[dst].
template<int D, bool BF16>
__global__ __launch_bounds__(256) void conv_kernel(const int* __restrict__ ei,
        const void* __restrict__ vecs, const float* __restrict__ invn,
        const float* __restrict__ hlin, float* __restrict__ acc) {
    const int wave = threadIdx.x >> 6, lane = threadIdx.x & 63;
    const int e = blockIdx.x * 4 + wave;
    const int src = ei[e];
    const int dst = ei[NE + e];
    float dot = 0.f;
    if (BF16) {
        const int4* sp = (const int4*)((const unsigned short*)vecs + (size_t)src * D);
        const int4* dp = (const int4*)((const unsigned short*)vecs + (size_t)dst * D);
        #pragma unroll
        for (int k = 0; k < D/512; k++) {
            union { int4 v; unsigned short u[8]; } sa, da;
            sa.v = sp[lane + k*64];
            da.v = dp[lane + k*64];
            #pragma unroll
            for (int j = 0; j < 8; j++) dot += bf2f(sa.u[j]) * bf2f(da.u[j]);
        }
    } else {
        const float4* sp = (const float4*)((const float*)vecs + (size_t)src * D);
        const float4* dp = (const float4*)((const float*)vecs + (size_t)dst * D);
        #pragma unroll
        for (int k = 0; k < D/256; k++) {
            float4 a4 = sp[lane + k*64];
            float4 b4 = dp[lane + k*64];
            dot += a4.x*b4.x + a4.y*b4.y + a4.z*b4.z + a4.w*b4.w;
        }
    }
    #pragma unroll
    for (int off = 32; off > 0; off >>= 1) dot += __shfl_down(dot, off);
    float w = __shfl(dot, 0);
    if (!BF16) w *= invn[src] * invn[dst];
    if (lane < 32) {
        atomicAdd(&acc[(size_t)dst * HC + lane], w * hlin[(size_t)src * HC + lane]);
    }
}

__global__ __launch_bounds__(256) void final_kernel(const float* __restrict__ ns,
        const float* __restrict__ hb, const float* __restrict__ hf,
        const float* __restrict__ pbW, const float* __restrict__ pbB,
        const float* __restrict__ pfW, const float* __restrict__ pfB,
        float* __restrict__ out) {
    const int i = blockIdx.x * 256 + threadIdx.x;
    float acc = ns[i] + pbB[0] + pfB[0];
    #pragma unroll
    for (int cc = 0; cc < HC; cc++)
        acc += hb[(size_t)i*HC + cc] * pbW[cc] + hf[(size_t)i*HC + cc] * pfW[cc];
    out[i] = acc;
}

extern "C" void kernel_launch(void* const* d_in, const int* in_sizes, int n_in,
                              void* d_out, int out_size, void* d_ws, size_t ws_size,
                              hipStream_t stream) {
    const float* x           = (const float*)d_in[0];
    const float* visual_body = (const float*)d_in[1];
    const float* visual_face = (const float*)d_in[2];
    const float* Wq     = (const float*)d_in[3];
    const float* Wk     = (const float*)d_in[4];
    const float* Wv     = (const float*)d_in[5];
    const float* ln_g   = (const float*)d_in[6];
    const float* ln_b   = (const float*)d_in[7];
    const float* prelu_a= (const float*)d_in[8];
    const float* mlp_W  = (const float*)d_in[9];
    const float* mlp_b  = (const float*)d_in[10];
    const float* np_W   = (const float*)d_in[11];
    const float* np_b   = (const float*)d_in[12];
    const float* body_W = (const float*)d_in[13];
    const float* body_b = (const float*)d_in[14];
    const float* face_W = (const float*)d_in[15];
    const float* face_b = (const float*)d_in[16];
    const float* pb_W   = (const float*)d_in[17];
    const float* pb_b   = (const float*)d_in[18];
    const float* pf_W   = (const float*)d_in[19];
    const float* pf_b   = (const float*)d_in[20];
    const int* ei_body  = (const int*)d_in[21];
    const int* ei_face  = (const int*)d_in[22];
    float* out = (float*)d_out;
    char* ws = (char*)d_ws;

    const size_t vnb_bytes = (size_t)NN*DB*2;          // 32 MB
    const size_t vnf_bytes = (size_t)NN*DF*2;          //  8 MB
    const size_t common_bytes = (size_t)NN*2*4 + 256 + (size_t)NN*4
                              + 4*(size_t)NN*HC*4 + 2*(size_t)NN*4;
    const bool bfp = ws_size >= vnb_bytes + vnf_bytes + common_bytes;

    size_t off = bfp ? (vnb_bytes + vnf_bytes) : 0;
    unsigned short* vn_body = (unsigned short*)ws;
    unsigned short* vn_face = (unsigned short*)(ws + vnb_bytes);
    float* a_ws  = (float*)(ws + off); off += (size_t)NN*2*4;
    float* stats = (float*)(ws + off); off += 256;
    float* ns    = (float*)(ws + off); off += (size_t)NN*4;
    float* hlb   = (float*)(ws + off); off += (size_t)NN*HC*4;
    float* hlf   = (float*)(ws + off); off += (size_t)NN*HC*4;
    float* hb    = (float*)(ws + off); off += (size_t)NN*HC*4;
    float* hf    = (float*)(ws + off); off += (size_t)NN*HC*4;
    float* invb  = (float*)(ws + off); off += (size_t)NN*4;
    float* invf  = (float*)(ws + off); off += (size_t)NN*4;

    // zero the two scatter accumulators (contiguous)
    hipMemsetAsync(hb, 0, 2*(size_t)NN*HC*4, stream);

    stats_kernel<<<1, 64, 0, stream>>>(Wq, Wk, Wv, stats);
    if (bfp) {
        norm_kernel<DB, true><<<NN, 256, 0, stream>>>(visual_body, vn_body, nullptr);
        norm_kernel<DF, true><<<NN, 256, 0, stream>>>(visual_face, vn_face, nullptr);
    } else {
        norm_kernel<DB, false><<<NN, 256, 0, stream>>>(visual_body, nullptr, invb);
        norm_kernel<DF, false><<<NN, 256, 0, stream>>>(visual_face, nullptr, invf);
    }
    attn_kernel<<<NB, 256, 0, stream>>>(x, stats, a_ws);
    node_kernel<<<NN/4, 256, 0, stream>>>(a_ws, stats, Wv, ln_g, ln_b, prelu_a,
        mlp_W, mlp_b, np_W, np_b, body_W, body_b, face_W, face_b, ns, hlb, hlf);
    if (bfp) {
        conv_kernel<DB, true><<<NE/4, 256, 0, stream>>>(ei_body, vn_body, nullptr, hlb, hb);
        conv_kernel<DF, true><<<NE/4, 256, 0, stream>>>(ei_face, vn_face, nullptr, hlf, hf);
    } else {
        conv_kernel<DB, false><<<NE/4, 256, 0, stream>>>(ei_body, visual_body, invb, hlb, hb);
        conv_kernel<DF, false><<<NE/4, 256, 0, stream>>>(ei_face, visual_face, invf, hlf, hf);
    }
    final_kernel<<<NN/256, 256, 0, stream>>>(ns, hb, hf, pb_W, pb_b, pf_W, pf_b, out);
}

// Round 2
// 303.023 us; speedup vs baseline: 1.0019x; 1.0019x over previous
//
#include <hip/hip_runtime.h>

#define NN 8192     // nodes
#define NB 32       // graphs
#define NG 256      // nodes per graph
#define NE 65536    // edges
#define DK 512
#define HC 32
#define DB 2048     // body visual dim
#define DF 512      // face visual dim

__device__ __forceinline__ float bf2f(unsigned short u) {
    return __uint_as_float(((unsigned int)u) << 16);
}
__device__ __forceinline__ unsigned short f2bf(float f) {
    unsigned int u = __float_as_uint(f);
    u += 0x7fffu + ((u >> 16) & 1u);   // round-to-nearest-even
    return (unsigned short)(u >> 16);
}
__device__ __forceinline__ float dot8bf(const int4 a, const int4 b) {
    union { int4 v; unsigned short u[8]; } A, B;
    A.v = a; B.v = b;
    float s = 0.f;
    #pragma unroll
    for (int j = 0; j < 8; j++) s += bf2f(A.u[j]) * bf2f(B.u[j]);
    return s;
}

// stats[0..3] = M_ab = sum_d Wq[a][d]*Wk[b][d]  (M00,M01,M10,M11)
// stats[4..5] = sum_d Wv[a][d]
// stats[6..8] = sum_d Wv[a][d]*Wv[b][d]  (q00,q01,q11)
__global__ void stats_kernel(const float* __restrict__ Wq, const float* __restrict__ Wk,
                             const float* __restrict__ Wv, float* __restrict__ stats) {
    const int lane = threadIdx.x;  // 64 threads
    float m00=0,m01=0,m10=0,m11=0,s0=0,s1=0,q00=0,q01=0,q11=0;
    for (int d = lane; d < DK; d += 64) {
        float q0=Wq[d], q1=Wq[DK+d];
        float k0=Wk[d], k1=Wk[DK+d];
        float v0=Wv[d], v1=Wv[DK+d];
        m00 += q0*k0; m01 += q0*k1; m10 += q1*k0; m11 += q1*k1;
        s0 += v0; s1 += v1;
        q00 += v0*v0; q01 += v0*v1; q11 += v1*v1;
    }
    #pragma unroll
    for (int off = 32; off > 0; off >>= 1) {
        m00 += __shfl_down(m00,off); m01 += __shfl_down(m01,off);
        m10 += __shfl_down(m10,off); m11 += __shfl_down(m11,off);
        s0  += __shfl_down(s0,off);  s1  += __shfl_down(s1,off);
        q00 += __shfl_down(q00,off); q01 += __shfl_down(q01,off);
        q11 += __shfl_down(q11,off);
    }
    if (lane == 0) {
        stats[0]=m00; stats[1]=m01; stats[2]=m10; stats[3]=m11;
        stats[4]=s0;  stats[5]=s1;  stats[6]=q00; stats[7]=q01; stats[8]=q11;
    }
}

// Normalize one visual row per block (body blocks [0,NN), face [NN,2NN)).
__global__ __launch_bounds__(256) void norm2_kernel(const float* __restrict__ vb,
        const float* __restrict__ vf, unsigned short* __restrict__ vnb,
        unsigned short* __restrict__ vnf) {
    __shared__ float red[4];
    __shared__ float s_inv;
    const bool body = blockIdx.x < NN;
    const int node = body ? blockIdx.x : blockIdx.x - NN;
    const int D = body ? DB : DF;
    const int tid = threadIdx.x;
    const float4* row = (const float4*)((body ? vb : vf) + (size_t)node * D);
    ushort4* orow = (ushort4*)((body ? vnb : vnf) + (size_t)node * D);
    float ss = 0.f;
    for (int c = tid; c < D/4; c += 256) {
        float4 x = row[c];
        ss += x.x*x.x + x.y*x.y + x.z*x.z + x.w*x.w;
    }
    #pragma unroll
    for (int off = 32; off > 0; off >>= 1) ss += __shfl_down(ss, off);
    if ((tid & 63) == 0) red[tid >> 6] = ss;
    __syncthreads();
    if (tid == 0) s_inv = rsqrtf(red[0]+red[1]+red[2]+red[3] + 1e-8f);
    __syncthreads();
    const float inv = s_inv;
    for (int c = tid; c < D/4; c += 256) {
        float4 x = row[c];
        orow[c] = make_ushort4(f2bf(x.x*inv), f2bf(x.y*inv),
                               f2bf(x.z*inv), f2bf(x.w*inv));
    }
}

// Rank-2 attention: one block per graph, one thread per query node.
__global__ __launch_bounds__(256) void attn_kernel(const float* __restrict__ x,
        const float* __restrict__ stats, float* __restrict__ a) {
    __shared__ float2 xs[NG];
    const int g = blockIdx.x, i = threadIdx.x;
    xs[i] = ((const float2*)x)[g*NG + i];
    __syncthreads();
    const float scale = 0.04419417382415922f;  // 1/sqrt(512)
    const float2 xi = xs[i];
    const float u0 = (xi.x*stats[0] + xi.y*stats[2]) * scale;
    const float u1 = (xi.x*stats[1] + xi.y*stats[3]) * scale;
    float m = -1e30f;
    for (int j = 0; j < NG; j++) {
        float s = u0*xs[j].x + u1*xs[j].y;
        m = fmaxf(m, s);
    }
    float S = 0.f, a0 = 0.f, a1 = 0.f;
    for (int j = 0; j < NG; j++) {
        float2 xj = xs[j];
        float p = __expf(u0*xj.x + u1*xj.y - m);
        S += p; a0 += p*xj.x; a1 += p*xj.y;
    }
    const float invS = 1.f / S;
    ((float2*)a)[g*NG + i] = make_float2(a0*invS, a1*invS);
}

// Per node (one wave each): reconstruct 512-d attn output from (a0,a1),
// closed-form LN stats, PReLU, 512->32 MLP, node score, and precompute
// h @ body_W / h @ face_W.
__global__ __launch_bounds__(256) void node_kernel(
        const float* __restrict__ a, const float* __restrict__ stats,
        const float* __restrict__ Wv,
        const float* __restrict__ ln_g, const float* __restrict__ ln_b,
        const float* __restrict__ prelu_a,
        const float* __restrict__ mlp_W, const float* __restrict__ mlp_b,
        const float* __restrict__ np_W, const float* __restrict__ np_b,
        const float* __restrict__ body_W, const float* __restrict__ body_b,
        const float* __restrict__ face_W, const float* __restrict__ face_b,
        float* __restrict__ ns, float* __restrict__ hlb, float* __restrict__ hlf) {
    __shared__ float t[4][DK];
    __shared__ float hbuf[4][HC];
    const int wave = threadIdx.x >> 6, lane = threadIdx.x & 63;
    const int node = blockIdx.x * 4 + wave;
    const float a0 = a[node*2], a1 = a[node*2+1];
    const float mean = (a0*stats[4] + a1*stats[5]) * (1.f/DK);
    const float msq  = (a0*a0*stats[6] + 2.f*a0*a1*stats[7] + a1*a1*stats[8]) * (1.f/DK);
    const float inv  = rsqrtf(msq - mean*mean + 1e-5f);
    const float alpha = prelu_a[0];
    const float4* wv0 = (const float4*)Wv;
    const float4* wv1 = (const float4*)(Wv + DK);
    const float4* g4 = (const float4*)ln_g;
    const float4* b4 = (const float4*)ln_b;
    #pragma unroll
    for (int k = 0; k < 2; k++) {
        int c4 = lane*2 + k;
        float4 w0 = wv0[c4], w1 = wv1[c4], gg = g4[c4], bb = b4[c4];
        const float* w0f = (const float*)&w0;
        const float* w1f = (const float*)&w1;
        const float* ggf = (const float*)&gg;
        const float* bbf = (const float*)&bb;
        #pragma unroll
        for (int e2 = 0; e2 < 4; e2++) {
            float od = a0*w0f[e2] + a1*w1f[e2];
            float nd = (od - mean) * inv * ggf[e2] + bbf[e2];
            t[wave][c4*4 + e2] = (nd >= 0.f) ? nd : alpha*nd;
        }
    }
    __syncthreads();
    // h_c = sum_d t[d] * mlp_W[d][c]; split d-range across the two half-waves
    const int c = lane & 31, half = lane >> 5;
    const float* tw = t[wave];
    const float* tp = tw + half*256;
    const float* mw = mlp_W + half*256*HC + c;
    float part = 0.f;
    for (int d = 0; d < 256; d++) part += tp[d] * mw[d*HC];
    part += __shfl_down(part, 32);
    float hc = 0.f;
    if (lane < 32) { hc = part + mlp_b[c]; hbuf[wave][c] = hc; }
    __syncthreads();
    // node score
    float sp = (lane < 32) ? hc * np_W[c] : 0.f;
    #pragma unroll
    for (int off = 16; off > 0; off >>= 1) sp += __shfl_down(sp, off);
    if (lane == 0) ns[node] = sp + np_b[0];
    // per-node linear for both convs
    const float* hb_ = hbuf[wave];
    if (lane < 32) {
        float acc2 = body_b[c];
        #pragma unroll 8
        for (int cp = 0; cp < HC; cp++) acc2 += hb_[cp] * body_W[cp*HC + c];
        hlb[(size_t)node*HC + c] = acc2;
    } else {
        float acc2 = face_b[c];
        #pragma unroll 8
        for (int cp = 0; cp < HC; cp++) acc2 += hb_[cp] * face_W[cp*HC + c];
        hlf[(size_t)node*HC + c] = acc2;
    }
}

// ---- CSR build (counting sort by dst) ----
__global__ __launch_bounds__(256) void count_kernel(const int* __restrict__ eib,
        const int* __restrict__ eif, int* __restrict__ counts) {
    const int e = blockIdx.x * 256 + threadIdx.x;   // [0, 2*NE)
    if (e < NE) atomicAdd(&counts[eib[NE + e]], 1);
    else        atomicAdd(&counts[NN + eif[NE + (e - NE)]], 1);
}

// One block per graph-type; exclusive scan of NN counts -> starts (NN+1) + cursor.
__global__ __launch_bounds__(256) void scan_kernel(const int* __restrict__ counts,
        int* __restrict__ starts, int* __restrict__ cursor) {
    __shared__ int part[256];
    const int cbase = blockIdx.x * NN;
    const int sbase = blockIdx.x * (NN + 1);
    const int t = threadIdx.x;
    int loc[32];
    int sum = 0;
    #pragma unroll
    for (int j = 0; j < 32; j++) { loc[j] = counts[cbase + t*32 + j]; sum += loc[j]; }
    part[t] = sum;
    __syncthreads();
    for (int off = 1; off < 256; off <<= 1) {
        int v = (t >= off) ? part[t - off] : 0;
        __syncthreads();
        part[t] += v;
        __syncthreads();
    }
    int run = (t == 0) ? 0 : part[t - 1];   // exclusive offset of this thread's chunk
    #pragma unroll
    for (int j = 0; j < 32; j++) {
        starts[sbase + t*32 + j] = run;
        cursor[cbase + t*32 + j] = run;
        run += loc[j];
    }
    if (t == 255) starts[sbase + NN] = run;
}

__global__ __launch_bounds__(256) void fill_kernel(const int* __restrict__ eib,
        const int* __restrict__ eif, int* __restrict__ cursor, int* __restrict__ esrc) {
    const int e = blockIdx.x * 256 + threadIdx.x;   // [0, 2*NE)
    if (e < NE) {
        int pos = atomicAdd(&cursor[eib[NE + e]], 1);
        esrc[pos] = eib[e];
    } else {
        int e2 = e - NE;
        int pos = atomicAdd(&cursor[NN + eif[NE + e2]], 1);
        esrc[NE + pos] = eif[e2];
    }
}

// One wave per dst node; dst row resident in registers; accumulate the
// 32-channel message in registers, reduce against pW, write one scalar.
// Blocks [0, NN/4): body. Blocks [NN/4, NN/2): face.
__global__ __launch_bounds__(256) void conv2_kernel(
        const unsigned short* __restrict__ vnb, const unsigned short* __restrict__ vnf,
        const int* __restrict__ starts, const int* __restrict__ esrc,
        const float* __restrict__ hlb, const float* __restrict__ hlf,
        const float* __restrict__ pbW, const float* __restrict__ pfW,
        float* __restrict__ gs) {
    const int wave = threadIdx.x >> 6, lane = threadIdx.x & 63;
    const bool body = blockIdx.x < (NN/4);
    const int node = (body ? blockIdx.x : blockIdx.x - NN/4) * 4 + wave;
    const int sbase = body ? 0 : (NN + 1);
    const int s0 = starts[sbase + node], s1 = starts[sbase + node + 1];
    float acc = 0.f;   // lanes 0..31 hold channel accumulators
    if (body) {
        const int4* drow = (const int4*)(vnb + (size_t)node * DB);
        int4 d0 = drow[lane], d1 = drow[lane+64], d2 = drow[lane+128], d3 = drow[lane+192];
        for (int e = s0; e < s1; e++) {
            const int src = esrc[e];
            const int4* srow = (const int4*)(vnb + (size_t)src * DB);
            int4 a0 = srow[lane], a1 = srow[lane+64], a2 = srow[lane+128], a3 = srow[lane+192];
            float dot = dot8bf(a0,d0) + dot8bf(a1,d1) + dot8bf(a2,d2) + dot8bf(a3,d3);
            #pragma unroll
            for (int off = 32; off > 0; off >>= 1) dot += __shfl_xor(dot, off);
            if (lane < 32) acc += dot * hlb[(size_t)src * HC + lane];
        }
    } else {
        const int4* drow = (const int4*)(vnf + (size_t)node * DF);
        int4 d0 = drow[lane];
        for (int e = s0; e < s1; e++) {
            const int src = esrc[NE + e];
            const int4* srow = (const int4*)(vnf + (size_t)src * DF);
            int4 a0 = srow[lane];
            float dot = dot8bf(a0, d0);
            #pragma unroll
            for (int off = 32; off > 0; off >>= 1) dot += __shfl_xor(dot, off);
            if (lane < 32) acc += dot * hlf[(size_t)src * HC + lane];
        }
    }
    float p = (lane < 32) ? acc * (body ? pbW : pfW)[lane] : 0.f;
    #pragma unroll
    for (int off = 16; off > 0; off >>= 1) p += __shfl_down(p, off);
    if (lane == 0) gs[(body ? 0 : NN) + node] = p;
}

__global__ __launch_bounds__(256) void final_kernel(const float* __restrict__ ns,
        const float* __restrict__ gs, const float* __restrict__ pbB,
        const float* __restrict__ pfB, float* __restrict__ out) {
    const int i = blockIdx.x * 256 + threadIdx.x;
    out[i] = ns[i] + gs[i] + gs[NN + i] + pbB[0] + pfB[0];
}

extern "C" void kernel_launch(void* const* d_in, const int* in_sizes, int n_in,
                              void* d_out, int out_size, void* d_ws, size_t ws_size,
                              hipStream_t stream) {
    const float* x           = (const float*)d_in[0];
    const float* visual_body = (const float*)d_in[1];
    const float* visual_face = (const float*)d_in[2];
    const float* Wq     = (const float*)d_in[3];
    const float* Wk     = (const float*)d_in[4];
    const float* Wv     = (const float*)d_in[5];
    const float* ln_g   = (const float*)d_in[6];
    const float* ln_b   = (const float*)d_in[7];
    const float* prelu_a= (const float*)d_in[8];
    const float* mlp_W  = (const float*)d_in[9];
    const float* mlp_b  = (const float*)d_in[10];
    const float* np_W   = (const float*)d_in[11];
    const float* np_b   = (const float*)d_in[12];
    const float* body_W = (const float*)d_in[13];
    const float* body_b = (const float*)d_in[14];
    const float* face_W = (const float*)d_in[15];
    const float* face_b = (const float*)d_in[16];
    const float* pb_W   = (const float*)d_in[17];
    const float* pb_b   = (const float*)d_in[18];
    const float* pf_W   = (const float*)d_in[19];
    const float* pf_b   = (const float*)d_in[20];
    const int* ei_body  = (const int*)d_in[21];
    const int* ei_face  = (const int*)d_in[22];
    float* out = (float*)d_out;
    char* ws = (char*)d_ws;

    size_t off = 0;
    auto alloc = [&](size_t bytes) { void* p = ws + off; off += (bytes + 15) & ~size_t(15); return p; };
    unsigned short* vn_body = (unsigned short*)alloc((size_t)NN*DB*2);  // 32 MB
    unsigned short* vn_face = (unsigned short*)alloc((size_t)NN*DF*2);  //  8 MB
    float* a_ws  = (float*)alloc((size_t)NN*2*4);
    float* stats = (float*)alloc(256);
    float* ns    = (float*)alloc((size_t)NN*4);
    float* hlb   = (float*)alloc((size_t)NN*HC*4);
    float* hlf   = (float*)alloc((size_t)NN*HC*4);
    float* gs    = (float*)alloc((size_t)2*NN*4);
    int* counts  = (int*)alloc((size_t)2*NN*4);
    int* starts  = (int*)alloc((size_t)2*(NN+1)*4);
    int* cursor  = (int*)alloc((size_t)2*NN*4);
    int* esrc    = (int*)alloc((size_t)2*NE*4);

    hipMemsetAsync(counts, 0, (size_t)2*NN*4, stream);

    stats_kernel<<<1, 64, 0, stream>>>(Wq, Wk, Wv, stats);
    norm2_kernel<<<2*NN, 256, 0, stream>>>(visual_body, visual_face, vn_body, vn_face);
    attn_kernel<<<NB, 256, 0, stream>>>(x, stats, a_ws);
    node_kernel<<<NN/4, 256, 0, stream>>>(a_ws, stats, Wv, ln_g, ln_b, prelu_a,
        mlp_W, mlp_b, np_W, np_b, body_W, body_b, face_W, face_b, ns, hlb, hlf);
    count_kernel<<<2*NE/256, 256, 0, stream>>>(ei_body, ei_face, counts);
    scan_kernel<<<2, 256, 0, stream>>>(counts, starts, cursor);
    fill_kernel<<<2*NE/256, 256, 0, stream>>>(ei_body, ei_face, cursor, esrc);
    conv2_kernel<<<NN/2, 256, 0, stream>>>(vn_body, vn_face, starts, esrc,
        hlb, hlf, pb_W, pf_W, gs);
    final_kernel<<<NN/256, 256, 0, stream>>>(ns, gs, pb_b, pf_b, out);
}

// Round 3
// 249.897 us; speedup vs baseline: 1.2149x; 1.2126x over previous
//
#include <hip/hip_runtime.h>

#define NN 8192     // nodes
#define NB 32       // graphs
#define NG 256      // nodes per graph
#define NE 65536    // edges per graph type
#define DK 512
#define HC 32
#define DB 2048     // body visual dim
#define DF 512      // face visual dim

typedef float v2f __attribute__((ext_vector_type(2)));

#if __has_builtin(__builtin_amdgcn_cvt_pk_f32_fp8) && __has_builtin(__builtin_amdgcn_cvt_pk_fp8_f32)
#define HW_FP8 1
#else
#define HW_FP8 0
#endif

// ---- fp8 e4m3fn helpers (manual fallback only used if builtins missing) ----
__device__ __forceinline__ float fp8_dec(unsigned u) {
    unsigned e = (u >> 3) & 15u, m = u & 7u, s = u & 0x80u;
    float v = e ? __uint_as_float(((e + 120u) << 23) | (m << 20))
                : (float)m * 0.001953125f;   // denormal: m * 2^-9
    return s ? -v : v;
}
__device__ __forceinline__ unsigned fp8_enc(float x) {
    unsigned sb = (__float_as_uint(x) >> 24) & 0x80u;
    float a = fabsf(x);
    if (a >= 448.f) return sb | 0x7Eu;
    if (a < 0.015625f) {                      // denormal range
        int c = (int)rintf(a * 512.f);
        if (c > 7) return sb | 0x08u;
        return sb | (unsigned)c;
    }
    int ex; (void)frexpf(a, &ex);             // a = f*2^ex, f in [0.5,1)
    float p = ldexpf(a, 1 - ex);              // [1,2)
    int m = (int)rintf((p - 1.f) * 8.f);
    int e = ex - 1 + 7;
    if (m == 8) { m = 0; e++; }
    if (e >= 16) return sb | 0x7Eu;
    return sb | (unsigned)(e << 3) | (unsigned)m;
}
__device__ __forceinline__ unsigned pack4_fp8(float x, float y, float z, float w) {
#if HW_FP8
    int u = __builtin_amdgcn_cvt_pk_fp8_f32(x, y, 0, false);
    u = __builtin_amdgcn_cvt_pk_fp8_f32(z, w, u, true);
    return (unsigned)u;
#else
    return fp8_enc(x) | (fp8_enc(y) << 8) | (fp8_enc(z) << 16) | (fp8_enc(w) << 24);
#endif
}
__device__ __forceinline__ float fp8dot4(unsigned a, unsigned b) {
#if HW_FP8
    v2f al = __builtin_amdgcn_cvt_pk_f32_fp8((int)a, false);
    v2f ah = __builtin_amdgcn_cvt_pk_f32_fp8((int)a, true);
    v2f bl = __builtin_amdgcn_cvt_pk_f32_fp8((int)b, false);
    v2f bh = __builtin_amdgcn_cvt_pk_f32_fp8((int)b, true);
    return al.x*bl.x + al.y*bl.y + ah.x*bh.x + ah.y*bh.y;
#else
    float s = 0.f;
    #pragma unroll
    for (int j = 0; j < 4; j++)
        s += fp8_dec((a >> (8*j)) & 255u) * fp8_dec((b >> (8*j)) & 255u);
    return s;
#endif
}
__device__ __forceinline__ float fp8dot16(int4 a, int4 b) {
    return fp8dot4((unsigned)a.x, (unsigned)b.x) + fp8dot4((unsigned)a.y, (unsigned)b.y)
         + fp8dot4((unsigned)a.z, (unsigned)b.z) + fp8dot4((unsigned)a.w, (unsigned)b.w);
}

// ================= L1: norm(fp8) + edge-count + attention =================
__global__ __launch_bounds__(256) void fused1_kernel(
        const float* __restrict__ vb, const float* __restrict__ vf,
        unsigned* __restrict__ vnb, unsigned* __restrict__ vnf,
        const int* __restrict__ eib, const int* __restrict__ eif,
        int* __restrict__ counts,
        const float* __restrict__ x, const float* __restrict__ Wq,
        const float* __restrict__ Wk, float* __restrict__ a_out) {
    __shared__ float red[4];
    __shared__ float s_inv;
    __shared__ float2 xs[NG];
    __shared__ float pm[4][4];
    __shared__ float sm4[4];
    const int bid = blockIdx.x, tid = threadIdx.x;
    const int lane = tid & 63, wave = tid >> 6;

    if (bid < 2*NN) {
        // ---- visual row normalize -> fp8 ----
        const bool body = bid < NN;
        const int node = body ? bid : bid - NN;
        const int D = body ? DB : DF;
        const float4* r4 = (const float4*)((body ? vb : vf) + (size_t)node * D);
        unsigned* orow = (body ? vnb : vnf) + (size_t)node * (D/4);
        float ss = 0.f;
        for (int c = tid; c < D/4; c += 256) {
            float4 q = r4[c];
            ss += q.x*q.x + q.y*q.y + q.z*q.z + q.w*q.w;
        }
        #pragma unroll
        for (int off = 32; off > 0; off >>= 1) ss += __shfl_down(ss, off);
        if (lane == 0) red[wave] = ss;
        __syncthreads();
        if (tid == 0) s_inv = rsqrtf(red[0]+red[1]+red[2]+red[3] + 1e-8f);
        __syncthreads();
        const float inv = s_inv;
        for (int c = tid; c < D/4; c += 256) {
            float4 q = r4[c];
            orow[c] = pack4_fp8(q.x*inv, q.y*inv, q.z*inv, q.w*inv);
        }
    } else if (bid < 2*NN + 512) {
        // ---- degree count (dst) ----
        const int e = (bid - 2*NN) * 256 + tid;     // [0, 2*NE)
        if (e < NE) atomicAdd(&counts[eib[NE + e]], 1);
        else        atomicAdd(&counts[NN + eif[NE + (e - NE)]], 1);
    } else {
        // ---- rank-2 attention, self-computed 2x2 M = Wq Wk^T ----
        const int g = bid - (2*NN + 512);
        xs[tid] = ((const float2*)x)[g*NG + tid];
        const int d = tid * 2;
        float q0a = Wq[d],      q0b = Wq[d+1];
        float q1a = Wq[DK+d],   q1b = Wq[DK+d+1];
        float k0a = Wk[d],      k0b = Wk[d+1];
        float k1a = Wk[DK+d],   k1b = Wk[DK+d+1];
        float m00 = q0a*k0a + q0b*k0b;
        float m01 = q0a*k1a + q0b*k1b;
        float m10 = q1a*k0a + q1b*k0b;
        float m11 = q1a*k1a + q1b*k1b;
        #pragma unroll
        for (int off = 32; off > 0; off >>= 1) {
            m00 += __shfl_down(m00,off); m01 += __shfl_down(m01,off);
            m10 += __shfl_down(m10,off); m11 += __shfl_down(m11,off);
        }
        if (lane == 0) { pm[wave][0]=m00; pm[wave][1]=m01; pm[wave][2]=m10; pm[wave][3]=m11; }
        __syncthreads();
        if (tid < 4) sm4[tid] = pm[0][tid] + pm[1][tid] + pm[2][tid] + pm[3][tid];
        __syncthreads();
        const float scale = 0.04419417382415922f;  // 1/sqrt(512)
        const float2 xi = xs[tid];
        const float u0 = (xi.x*sm4[0] + xi.y*sm4[2]) * scale;
        const float u1 = (xi.x*sm4[1] + xi.y*sm4[3]) * scale;
        float m = -1e30f;
        for (int j = 0; j < NG; j++) m = fmaxf(m, u0*xs[j].x + u1*xs[j].y);
        float S = 0.f, a0 = 0.f, a1 = 0.f;
        for (int j = 0; j < NG; j++) {
            float2 xj = xs[j];
            float p = __expf(u0*xj.x + u1*xj.y - m);
            S += p; a0 += p*xj.x; a1 += p*xj.y;
        }
        const float invS = 1.f / S;
        ((float2*)a_out)[g*NG + tid] = make_float2(a0*invS, a1*invS);
    }
}

// ================= L2: CSR scan + per-node MLP pipeline =================
__global__ __launch_bounds__(256) void fused2_kernel(
        const int* __restrict__ counts, int* __restrict__ starts, int* __restrict__ cursor,
        const float* __restrict__ a_in, const float* __restrict__ Wv,
        const float* __restrict__ ln_g, const float* __restrict__ ln_b,
        const float* __restrict__ prelu_a,
        const float* __restrict__ mlp_W, const float* __restrict__ mlp_b,
        const float* __restrict__ np_W, const float* __restrict__ np_b,
        const float* __restrict__ body_W, const float* __restrict__ body_b,
        const float* __restrict__ face_W, const float* __restrict__ face_b,
        float* __restrict__ ns, float* __restrict__ hlb, float* __restrict__ hlf) {
    __shared__ int part[256];
    __shared__ float t[4][DK];
    __shared__ float hbuf[4][HC];
    const int bid = blockIdx.x, tid = threadIdx.x;

    if (bid < 2) {
        // ---- exclusive scan over NN counts ----
        const int cbase = bid * NN;
        const int sbase = bid * (NN + 1);
        int loc[32];
        int sum = 0;
        #pragma unroll
        for (int j = 0; j < 32; j++) { loc[j] = counts[cbase + tid*32 + j]; sum += loc[j]; }
        part[tid] = sum;
        __syncthreads();
        for (int off = 1; off < 256; off <<= 1) {
            int v = (tid >= off) ? part[tid - off] : 0;
            __syncthreads();
            part[tid] += v;
            __syncthreads();
        }
        int run = (tid == 0) ? 0 : part[tid - 1];
        #pragma unroll
        for (int j = 0; j < 32; j++) {
            starts[sbase + tid*32 + j] = run;
            cursor[cbase + tid*32 + j] = run;
            run += loc[j];
        }
        if (tid == 255) starts[sbase + NN] = run;
        return;
    }
    // ---- node pipeline: closed-form LN + PReLU + MLP + scores ----
    const int wave = tid >> 6, lane = tid & 63;
    const int node = (bid - 2) * 4 + wave;
    const float a0 = a_in[node*2], a1 = a_in[node*2+1];
    const float4* wv0 = (const float4*)Wv;
    const float4* wv1 = (const float4*)(Wv + DK);
    const float4* g4 = (const float4*)ln_g;
    const float4* b4 = (const float4*)ln_b;
    float4 W0[2], W1[2], Gg[2], Bb[2];
    #pragma unroll
    for (int k = 0; k < 2; k++) {
        int c4 = lane*2 + k;
        W0[k] = wv0[c4]; W1[k] = wv1[c4]; Gg[k] = g4[c4]; Bb[k] = b4[c4];
    }
    // self-stats for closed-form LayerNorm over the rank-2 output
    float s0=0.f, s1=0.f, q00=0.f, q01=0.f, q11=0.f;
    #pragma unroll
    for (int k = 0; k < 2; k++) {
        const float* u = (const float*)&W0[k];
        const float* v = (const float*)&W1[k];
        #pragma unroll
        for (int j = 0; j < 4; j++) {
            s0 += u[j]; s1 += v[j];
            q00 += u[j]*u[j]; q01 += u[j]*v[j]; q11 += v[j]*v[j];
        }
    }
    #pragma unroll
    for (int off = 1; off < 64; off <<= 1) {
        s0 += __shfl_xor(s0,off); s1 += __shfl_xor(s1,off);
        q00 += __shfl_xor(q00,off); q01 += __shfl_xor(q01,off); q11 += __shfl_xor(q11,off);
    }
    const float mean = (a0*s0 + a1*s1) * (1.f/DK);
    const float msq  = (a0*a0*q00 + 2.f*a0*a1*q01 + a1*a1*q11) * (1.f/DK);
    const float inv  = rsqrtf(msq - mean*mean + 1e-5f);
    const float alpha = prelu_a[0];
    #pragma unroll
    for (int k = 0; k < 2; k++) {
        int c4 = lane*2 + k;
        const float* u = (const float*)&W0[k];
        const float* v = (const float*)&W1[k];
        const float* gf = (const float*)&Gg[k];
        const float* bf = (const float*)&Bb[k];
        #pragma unroll
        for (int j = 0; j < 4; j++) {
            float od = a0*u[j] + a1*v[j];
            float nd = (od - mean) * inv * gf[j] + bf[j];
            t[wave][c4*4 + j] = (nd >= 0.f) ? nd : alpha*nd;
        }
    }
    __syncthreads();
    const int c = lane & 31, half = lane >> 5;
    const float* tp = t[wave] + half*256;
    const float* mw = mlp_W + half*256*HC + c;
    float partl = 0.f;
    for (int d = 0; d < 256; d++) partl += tp[d] * mw[d*HC];
    partl += __shfl_down(partl, 32);
    float hc = 0.f;
    if (lane < 32) { hc = partl + mlp_b[c]; hbuf[wave][c] = hc; }
    __syncthreads();
    float sp = (lane < 32) ? hc * np_W[c] : 0.f;
    #pragma unroll
    for (int off = 16; off > 0; off >>= 1) sp += __shfl_down(sp, off);
    if (lane == 0) ns[node] = sp + np_b[0];
    const float* hb_ = hbuf[wave];
    if (lane < 32) {
        float acc2 = body_b[c];
        #pragma unroll 8
        for (int cp = 0; cp < HC; cp++) acc2 += hb_[cp] * body_W[cp*HC + c];
        hlb[(size_t)node*HC + c] = acc2;
    } else {
        float acc2 = face_b[c];
        #pragma unroll 8
        for (int cp = 0; cp < HC; cp++) acc2 += hb_[cp] * face_W[cp*HC + c];
        hlf[(size_t)node*HC + c] = acc2;
    }
}

// ================= L3: CSR fill (src + dst per slot) =================
__global__ __launch_bounds__(256) void fill_kernel(const int* __restrict__ eib,
        const int* __restrict__ eif, int* __restrict__ cursor,
        int* __restrict__ esrc, int* __restrict__ edst) {
    const int e = blockIdx.x * 256 + threadIdx.x;   // [0, 2*NE)
    if (e < NE) {
        int s = eib[e], d = eib[NE + e];
        int pos = atomicAdd(&cursor[d], 1);
        esrc[pos] = s; edst[pos] = d;
    } else {
        int e2 = e - NE;
        int s = eif[e2], d = eif[NE + e2];
        int pos = atomicAdd(&cursor[NN + d], 1);
        esrc[NE + pos] = s; edst[NE + pos] = d;
    }
}

// ================= L4: edge cosines in CSR order (2 edges / wave) =================
__global__ __launch_bounds__(256) void wdot_kernel(const int* __restrict__ esrc,
        const int* __restrict__ edst, const unsigned* __restrict__ vnb,
        const unsigned* __restrict__ vnf, float* __restrict__ w) {
    const int wave = threadIdx.x >> 6, lane = threadIdx.x & 63;
    const int base = (blockIdx.x * 4 + wave) * 2;
    float dot0, dot1;
    int i0;
    if (base < NE) {
        i0 = base;
        const int s0 = esrc[i0], d0 = edst[i0], s1 = esrc[i0+1], d1 = edst[i0+1];
        const int4* A = (const int4*)(vnb + (size_t)s0 * (DB/4));
        const int4* Bp = (const int4*)(vnb + (size_t)d0 * (DB/4));
        const int4* C = (const int4*)(vnb + (size_t)s1 * (DB/4));
        const int4* E = (const int4*)(vnb + (size_t)d1 * (DB/4));
        int4 a0 = A[lane],  a1 = A[lane+64];
        int4 b0 = Bp[lane], b1 = Bp[lane+64];
        int4 c0 = C[lane],  c1 = C[lane+64];
        int4 e0 = E[lane],  e1 = E[lane+64];
        dot0 = fp8dot16(a0,b0) + fp8dot16(a1,b1);
        dot1 = fp8dot16(c0,e0) + fp8dot16(c1,e1);
    } else {
        i0 = base;                        // slot in face region (already offset by NE)
        const int s0 = esrc[i0], d0 = edst[i0], s1 = esrc[i0+1], d1 = edst[i0+1];
        const int2* A = (const int2*)(vnf + (size_t)s0 * (DF/4));
        const int2* Bp = (const int2*)(vnf + (size_t)d0 * (DF/4));
        const int2* C = (const int2*)(vnf + (size_t)s1 * (DF/4));
        const int2* E = (const int2*)(vnf + (size_t)d1 * (DF/4));
        int2 a = A[lane], b = Bp[lane], c = C[lane], e = E[lane];
        dot0 = fp8dot4((unsigned)a.x,(unsigned)b.x) + fp8dot4((unsigned)a.y,(unsigned)b.y);
        dot1 = fp8dot4((unsigned)c.x,(unsigned)e.x) + fp8dot4((unsigned)c.y,(unsigned)e.y);
    }
    #pragma unroll
    for (int off = 1; off < 64; off <<= 1) {
        dot0 += __shfl_xor(dot0, off);
        dot1 += __shfl_xor(dot1, off);
    }
    if (lane == 0) ((float2*)w)[i0 >> 1] = make_float2(dot0, dot1);
}

// ================= L5: CSR gather + projections + final sum =================
__global__ __launch_bounds__(256) void gather_kernel(const int* __restrict__ starts,
        const int* __restrict__ esrc, const float* __restrict__ w,
        const float* __restrict__ hlb, const float* __restrict__ hlf,
        const float* __restrict__ ns,
        const float* __restrict__ pbW, const float* __restrict__ pbB,
        const float* __restrict__ pfW, const float* __restrict__ pfB,
        float* __restrict__ out) {
    const int wave = threadIdx.x >> 6, lane = threadIdx.x & 63;
    const int node = blockIdx.x * 4 + wave;
    const bool bodyhalf = lane < 32;
    const int c = lane & 31;
    const int sbase = bodyhalf ? 0 : (NN + 1);
    const int eofs = bodyhalf ? 0 : NE;
    const float* hl = bodyhalf ? hlb : hlf;
    const int s0 = starts[sbase + node], s1 = starts[sbase + node + 1];
    float acc = 0.f;
    for (int i = s0; i < s1; i++) {
        float wv = w[eofs + i];
        int s = esrc[eofs + i];
        acc += wv * hl[(size_t)s * HC + c];
    }
    float p = acc * (bodyhalf ? pbW : pfW)[c];
    #pragma unroll
    for (int off = 16; off > 0; off >>= 1) p += __shfl_down(p, off);
    float tot = __shfl(p, 0) + __shfl(p, 32);
    if (lane == 0) out[node] = ns[node] + tot + pbB[0] + pfB[0];
}

extern "C" void kernel_launch(void* const* d_in, const int* in_sizes, int n_in,
                              void* d_out, int out_size, void* d_ws, size_t ws_size,
                              hipStream_t stream) {
    const float* x           = (const float*)d_in[0];
    const float* visual_body = (const float*)d_in[1];
    const float* visual_face = (const float*)d_in[2];
    const float* Wq     = (const float*)d_in[3];
    const float* Wk     = (const float*)d_in[4];
    const float* Wv     = (const float*)d_in[5];
    const float* ln_g   = (const float*)d_in[6];
    const float* ln_b   = (const float*)d_in[7];
    const float* prelu_a= (const float*)d_in[8];
    const float* mlp_W  = (const float*)d_in[9];
    const float* mlp_b  = (const float*)d_in[10];
    const float* np_W   = (const float*)d_in[11];
    const float* np_b   = (const float*)d_in[12];
    const float* body_W = (const float*)d_in[13];
    const float* body_b = (const float*)d_in[14];
    const float* face_W = (const float*)d_in[15];
    const float* face_b = (const float*)d_in[16];
    const float* pb_W   = (const float*)d_in[17];
    const float* pb_b   = (const float*)d_in[18];
    const float* pf_W   = (const float*)d_in[19];
    const float* pf_b   = (const float*)d_in[20];
    const int* ei_body  = (const int*)d_in[21];
    const int* ei_face  = (const int*)d_in[22];
    float* out = (float*)d_out;
    char* ws = (char*)d_ws;

    size_t off = 0;
    auto alloc = [&](size_t bytes) { void* p = ws + off; off += (bytes + 15) & ~size_t(15); return p; };
    unsigned* vn_body = (unsigned*)alloc((size_t)NN*(DB/4)*4);   // 16 MB fp8
    unsigned* vn_face = (unsigned*)alloc((size_t)NN*(DF/4)*4);   //  4 MB fp8
    float* a_ws  = (float*)alloc((size_t)NN*2*4);
    float* ns    = (float*)alloc((size_t)NN*4);
    float* hlb   = (float*)alloc((size_t)NN*HC*4);
    float* hlf   = (float*)alloc((size_t)NN*HC*4);
    int* counts  = (int*)alloc((size_t)2*NN*4);
    int* starts  = (int*)alloc((size_t)2*(NN+1)*4);
    int* cursor  = (int*)alloc((size_t)2*NN*4);
    int* esrc    = (int*)alloc((size_t)2*NE*4);
    int* edst    = (int*)alloc((size_t)2*NE*4);
    float* w     = (float*)alloc((size_t)2*NE*4);

    hipMemsetAsync(counts, 0, (size_t)2*NN*4, stream);
    fused1_kernel<<<2*NN + 512 + NB, 256, 0, stream>>>(
        visual_body, visual_face, vn_body, vn_face, ei_body, ei_face, counts,
        x, Wq, Wk, a_ws);
    fused2_kernel<<<2 + NN/4, 256, 0, stream>>>(
        counts, starts, cursor, a_ws, Wv, ln_g, ln_b, prelu_a,
        mlp_W, mlp_b, np_W, np_b, body_W, body_b, face_W, face_b, ns, hlb, hlf);
    fill_kernel<<<2*NE/256, 256, 0, stream>>>(ei_body, ei_face, cursor, esrc, edst);
    wdot_kernel<<<2*NE/8, 256, 0, stream>>>(esrc, edst, vn_body, vn_face, w);
    gather_kernel<<<NN/4, 256, 0, stream>>>(starts, esrc, w, hlb, hlf, ns,
        pb_W, pb_b, pf_W, pf_b, out);
}